// Round 1
// baseline (1269.260 us; speedup 1.0000x reference)
//
#include <hip/hip_runtime.h>

typedef unsigned short u16;
typedef unsigned int u32;
typedef __attribute__((ext_vector_type(8))) short short8;
typedef __attribute__((ext_vector_type(8))) u16 u16x8;
typedef __attribute__((ext_vector_type(4))) u16 u16x4;
typedef __attribute__((ext_vector_type(4))) float f32x4;

#define DEVINL static __device__ __forceinline__

DEVINL float bf2f(u16 u) { return __uint_as_float(((u32)u) << 16); }
DEVINL u16 f2bf(float f) {  // RNE round to bf16
  u32 x = __float_as_uint(f);
  u32 r = (x + 0x7fffu + ((x >> 16) & 1u)) >> 16;
  return (u16)r;
}
DEVINL float fast_tanh(float x) {
  float cx = fminf(fmaxf(x, -15.f), 15.f);
  float e = __expf(2.f * cx);
  return (e - 1.f) / (e + 1.f);
}
DEVINL float sigm(float x) { return 1.f / (1.f + __expf(-x)); }

typedef __attribute__((address_space(1))) const void gvoid;
typedef __attribute__((address_space(3))) void svoid;
DEVINL void gld16(const void* g, void* l) {
  __builtin_amdgcn_global_load_lds((gvoid*)g, (svoid*)l, 16, 0, 0);
}

// ---------------------------------------------------------------------------
// Phase 1: cast / gather / permute everything once. One grid-stride kernel,
// region-dispatched by linear index.
// Regions (element counts):
//  0 feat_bf   12845056  features f32 -> bf16
//  1 Waf_bf     1048576  W_attn_feat [512][2048] -> bf16
//  2 WahT8      262144   W_attn_h -> [k/8][r=512][8] bf16 (coalesced ph reads)
//  3 Wcat       5242880  [2048 perm rows][2560]: k<2048 -> W_ih[:,512+k], else W_hh
//  4 Wemb       1048576  [2048 perm rows][512] = W_ih[:, :512]
//  5 bias_perm  2048     (b_ih + b_hh)[perm]
//  6 Wout_bf    5177344  [10112 pad][512], pad rows = 0
//  7 emb_bf     2097152  [m=t*128+b][512] = embed_w[captions[b][t]]
//  8 zeros_bf   512
//  9 c_state    65536    = 0
// perm row r <-> orig gate row o = (r&3)*512 + (r>>2)   (i,f,g,o interleave)
// ---------------------------------------------------------------------------
__global__ __launch_bounds__(256) void cast_all(
    const float* __restrict__ features, const int* __restrict__ captions,
    const float* __restrict__ embed_w, const float* __restrict__ Waf,
    const float* __restrict__ Wah, const float* __restrict__ W_ih,
    const float* __restrict__ W_hh, const float* __restrict__ b_ih,
    const float* __restrict__ b_hh, const float* __restrict__ W_out,
    u16* __restrict__ feat_bf, u16* __restrict__ Waf_bf,
    u16* __restrict__ WahT8, u16* __restrict__ Wcat, u16* __restrict__ Wemb,
    float* __restrict__ bias_perm, u16* __restrict__ Wout_bf,
    u16* __restrict__ emb_bf, u16* __restrict__ zeros_bf,
    float* __restrict__ c_state) {
  long long i = (long long)blockIdx.x * 256 + threadIdx.x;
  const long long total = 27789824LL;
  const long long stride = (long long)gridDim.x * 256;
  for (; i < total; i += stride) {
    long long r = i;
    if (r < 12845056LL) { feat_bf[r] = f2bf(features[r]); continue; }
    r -= 12845056LL;
    if (r < 1048576LL) { Waf_bf[r] = f2bf(Waf[r]); continue; }
    r -= 1048576LL;
    if (r < 262144LL) {
      long long kb = r >> 12, rem = r & 4095;
      long long row = rem >> 3, e = rem & 7;
      WahT8[r] = f2bf(Wah[row * 512 + (kb * 8 + e)]);
      continue;
    }
    r -= 262144LL;
    if (r < 5242880LL) {
      long long pr = r / 2560, k = r % 2560;
      long long o = (pr & 3) * 512 + (pr >> 2);
      float v = (k < 2048) ? W_ih[o * 2560 + 512 + k] : W_hh[o * 512 + (k - 2048)];
      Wcat[r] = f2bf(v);
      continue;
    }
    r -= 5242880LL;
    if (r < 1048576LL) {
      long long pr = r >> 9, k = r & 511;
      long long o = (pr & 3) * 512 + (pr >> 2);
      Wemb[r] = f2bf(W_ih[o * 2560 + k]);
      continue;
    }
    r -= 1048576LL;
    if (r < 2048LL) {
      long long o = (r & 3) * 512 + (r >> 2);
      bias_perm[r] = b_ih[o] + b_hh[o];
      continue;
    }
    r -= 2048LL;
    if (r < 5177344LL) {
      long long row = r >> 9, k = r & 511;
      Wout_bf[r] = (row < 10000) ? f2bf(W_out[row * 512 + k]) : (u16)0;
      continue;
    }
    r -= 5177344LL;
    if (r < 2097152LL) {
      long long m = r >> 9, k = r & 511;
      long long tt = m >> 7, b = m & 127;
      int tok = captions[b * 32 + tt];
      tok = tok < 0 ? 0 : (tok > 9999 ? 9999 : tok);
      emb_bf[r] = f2bf(embed_w[(long long)tok * 512 + k]);
      continue;
    }
    r -= 2097152LL;
    if (r < 512LL) { zeros_bf[r] = 0; continue; }
    r -= 512LL;
    c_state[r] = 0.f;
  }
}

// ---------------------------------------------------------------------------
// Generic 128x128 bf16 MFMA GEMM: C[m][n] = sum_k A[m][k]*B[n][k] (+bias[n]).
// A:[M][K] bf16, B:[N][K] bf16 (B^T layout), C f32 with row stride ldC.
// M,N multiples of 128 (grid), store-guard col<Nvalid. K multiple of 32.
// T3 minimal 2-phase double-buffer with global_load_lds width-16 staging.
// MFMA 16x16x32_bf16; A/B k-slot bijection k=(lane/16)*8+e (same for both).
// ---------------------------------------------------------------------------
__global__ __launch_bounds__(256) void gemm128(
    const u16* __restrict__ A, const u16* __restrict__ B,
    float* __restrict__ C, const float* __restrict__ bias,
    int K, int ldC, int Nvalid) {
  const int n0 = blockIdx.x * 128, m0 = blockIdx.y * 128;
  const int tid = threadIdx.x, w = tid >> 6, l = tid & 63;
  const int wm = w >> 1, wn = w & 1;
  __shared__ __align__(16) u16 As[2][128 * 32];
  __shared__ __align__(16) u16 Bs[2][128 * 32];
  const f32x4 z4 = {0.f, 0.f, 0.f, 0.f};
  f32x4 acc[4][4];
#pragma unroll
  for (int a_ = 0; a_ < 4; ++a_)
#pragma unroll
    for (int b_ = 0; b_ < 4; ++b_) acc[a_][b_] = z4;

  const int NT = K >> 5;
  const size_t rs = (size_t)K * 2;  // row bytes

  auto stage = [&](int buf, int kt) {
    const char* Ab = (const char*)A + (size_t)m0 * rs + (size_t)kt * 64;
    const char* Bb = (const char*)B + (size_t)n0 * rs + (size_t)kt * 64;
#pragma unroll
    for (int j = 0; j < 2; ++j) {
      int c = j * 256 + tid;
      int row = c >> 2, off = (c & 3) * 16;
      char* la = (char*)&As[buf][0] + (size_t)(j * 256 + w * 64) * 16;
      char* lb = (char*)&Bs[buf][0] + (size_t)(j * 256 + w * 64) * 16;
      gld16(Ab + (size_t)row * rs + off, la);
      gld16(Bb + (size_t)row * rs + off, lb);
    }
  };

  stage(0, 0);
  int cur = 0;
  const int lg = l >> 4, lr = l & 15;
  for (int kt = 0; kt < NT; ++kt) {
    __syncthreads();
    if (kt + 1 < NT) stage(cur ^ 1, kt + 1);
    short8 a[4], bb[4];
#pragma unroll
    for (int mi = 0; mi < 4; ++mi)
      a[mi] = *(const short8*)&As[cur][(wm * 64 + mi * 16 + lr) * 32 + lg * 8];
#pragma unroll
    for (int ni = 0; ni < 4; ++ni)
      bb[ni] = *(const short8*)&Bs[cur][(wn * 64 + ni * 16 + lr) * 32 + lg * 8];
#pragma unroll
    for (int mi = 0; mi < 4; ++mi)
#pragma unroll
      for (int ni = 0; ni < 4; ++ni)
        acc[mi][ni] = __builtin_amdgcn_mfma_f32_16x16x32_bf16(a[mi], bb[ni], acc[mi][ni], 0, 0, 0);
    cur ^= 1;
  }
  // epilogue: D frag mapping col=lane&15, row=(lane>>4)*4+reg  [m89-verified]
#pragma unroll
  for (int ni = 0; ni < 4; ++ni) {
    int col = n0 + wn * 64 + ni * 16 + lr;
    if (col >= Nvalid) continue;
    float bv = bias ? bias[col] : 0.f;
#pragma unroll
    for (int mi = 0; mi < 4; ++mi) {
      int rowb = m0 + wm * 64 + mi * 16 + lg * 4;
#pragma unroll
      for (int r = 0; r < 4; ++r)
        C[(size_t)(rowb + r) * ldC + col] = acc[mi][ni][r] + bv;
    }
  }
}

// ---------------------------------------------------------------------------
// Per-step attention kernel. One block per batch b, 512 threads.
// For t>0: first finish step t-1's LSTM (sum 4 K-split gate partials +
// emb_pre, gate math) producing h_t (kept in LDS for ph; stored bf16 in
// h_all[b][t-1]); then ph = h_t @ W_attn_h^T, scores=tanh(pf+ph)@w_score,
// softmax over N=49, ctx = alpha @ features -> ctx_bf (bf16).
// ---------------------------------------------------------------------------
__global__ __launch_bounds__(512) void attn_step(
    int t, const float* __restrict__ gates_part,  // [4][128][2048]
    const float* __restrict__ emb_pre,            // [32][128][2048]
    float* __restrict__ c_state,                  // [128][512]
    u16* __restrict__ h_all,                      // [128][32][512] bf16
    const u16* __restrict__ WahT8,                // [64][512][8] bf16
    const float* __restrict__ w_score,            // [512]
    const float* __restrict__ proj_feat,          // [128][49][512]
    const u16* __restrict__ feat_bf,              // [128][49][2048] bf16
    u16* __restrict__ ctx_bf) {                   // [128][2048] bf16
  const int b = blockIdx.x, tid = threadIdx.x;
  __shared__ float h_s[512], ph_s[512], ws_s[512];
  __shared__ float al_s[64];
  ws_s[tid] = w_score[tid];

  float hval = 0.f;
  if (t > 0) {
    const int j = tid;
    const float* gp = gates_part + (size_t)b * 2048 + 4 * j;
    const size_t ss = (size_t)128 * 2048;
    float4 g0 = *(const float4*)gp;
    float4 g1 = *(const float4*)(gp + ss);
    float4 g2 = *(const float4*)(gp + 2 * ss);
    float4 g3 = *(const float4*)(gp + 3 * ss);
    float4 ep = *(const float4*)(emb_pre + ((size_t)(t - 1) * 128 + b) * 2048 + 4 * j);
    float iv = g0.x + g1.x + g2.x + g3.x + ep.x;
    float fv = g0.y + g1.y + g2.y + g3.y + ep.y;
    float gv = g0.z + g1.z + g2.z + g3.z + ep.z;
    float ov = g0.w + g1.w + g2.w + g3.w + ep.w;
    float c_old = c_state[b * 512 + j];
    float cn = sigm(fv) * c_old + sigm(iv) * fast_tanh(gv);
    hval = sigm(ov) * fast_tanh(cn);
    c_state[b * 512 + j] = cn;
    h_all[((size_t)b * 32 + (t - 1)) * 512 + j] = f2bf(hval);
  }
  h_s[tid] = hval;
  __syncthreads();

  float ph = 0.f;
  if (t > 0) {
#pragma unroll 4
    for (int kb = 0; kb < 64; ++kb) {
      u16x8 wv = *(const u16x8*)(WahT8 + (size_t)kb * 4096 + tid * 8);
#pragma unroll
      for (int e = 0; e < 8; ++e) ph = fmaf(bf2f(wv[e]), h_s[kb * 8 + e], ph);
    }
  }
  ph_s[tid] = ph;
  __syncthreads();

  const int wv_ = tid >> 6, ln = tid & 63;
  for (int n = wv_; n < 49; n += 8) {
    const float* pf = proj_feat + ((size_t)b * 49 + n) * 512 + ln * 8;
    float4 p0 = *(const float4*)pf;
    float4 p1 = *(const float4*)(pf + 4);
    const int k0 = ln * 8;
    float s;
    s  = fast_tanh(p0.x + ph_s[k0 + 0]) * ws_s[k0 + 0];
    s += fast_tanh(p0.y + ph_s[k0 + 1]) * ws_s[k0 + 1];
    s += fast_tanh(p0.z + ph_s[k0 + 2]) * ws_s[k0 + 2];
    s += fast_tanh(p0.w + ph_s[k0 + 3]) * ws_s[k0 + 3];
    s += fast_tanh(p1.x + ph_s[k0 + 4]) * ws_s[k0 + 4];
    s += fast_tanh(p1.y + ph_s[k0 + 5]) * ws_s[k0 + 5];
    s += fast_tanh(p1.z + ph_s[k0 + 6]) * ws_s[k0 + 6];
    s += fast_tanh(p1.w + ph_s[k0 + 7]) * ws_s[k0 + 7];
#pragma unroll
    for (int off = 32; off > 0; off >>= 1) s += __shfl_down(s, off);
    if (ln == 0) al_s[n] = s;
  }
  __syncthreads();
  if (tid < 64) {
    float v = (tid < 49) ? al_s[tid] : -1e30f;
    float m = v;
#pragma unroll
    for (int off = 32; off > 0; off >>= 1) m = fmaxf(m, __shfl_xor(m, off));
    float e = (tid < 49) ? __expf(v - m) : 0.f;
    float sm = e;
#pragma unroll
    for (int off = 32; off > 0; off >>= 1) sm += __shfl_xor(sm, off);
    if (tid < 49) al_s[tid] = e / sm;
  }
  __syncthreads();

  float c0 = 0, c1 = 0, c2 = 0, c3 = 0;
  const u16* fb = feat_bf + (size_t)b * 49 * 2048 + tid * 4;
  for (int n = 0; n < 49; ++n) {
    float a = al_s[n];
    u16x4 v = *(const u16x4*)(fb + (size_t)n * 2048);
    c0 = fmaf(bf2f(v[0]), a, c0);
    c1 = fmaf(bf2f(v[1]), a, c1);
    c2 = fmaf(bf2f(v[2]), a, c2);
    c3 = fmaf(bf2f(v[3]), a, c3);
  }
  u16x4 o;
  o[0] = f2bf(c0); o[1] = f2bf(c1); o[2] = f2bf(c2); o[3] = f2bf(c3);
  *(u16x4*)(ctx_bf + (size_t)b * 2048 + tid * 4) = o;
}

// ---------------------------------------------------------------------------
// Per-step gates GEMM, K-split x4 into disjoint partial buffers (no atomics).
// grid (ns=16, bt=4, ks=4), 256 thr. Block: 32 batch rows x 128 perm gate
// rows over K-quarter 640. x = [ctx(2048) | h(512)]; h staged from
// h_all[b][t-1] (zeros for t=0). LDS rows are 128B -> XOR byte-swizzle
// (^(row&7)<<4) applied on pre-swizzled global source + swizzled ds_read
// (rule 21: linear gld_lds dest).
// ---------------------------------------------------------------------------
__global__ __launch_bounds__(256) void gates_step(
    int t, const u16* __restrict__ ctx_bf,   // [128][2048]
    const u16* __restrict__ h_all,           // [128][32][512]
    const u16* __restrict__ zeros_bf,        // [512]
    const u16* __restrict__ Wcat,            // [2048][2560] perm rows
    float* __restrict__ gates_part) {        // [4][128][2048]
  const int ns = blockIdx.x, bt = blockIdx.y, ks = blockIdx.z;
  const int b0 = bt * 32, row0 = ns * 128;
  const int tid = threadIdx.x, w = tid >> 6, l = tid & 63;
  __shared__ __align__(16) u16 Xs[2][32 * 64];
  __shared__ __align__(16) u16 Ws[2][128 * 64];
  const f32x4 z4 = {0.f, 0.f, 0.f, 0.f};
  f32x4 acc[2][2];
  acc[0][0] = z4; acc[0][1] = z4; acc[1][0] = z4; acc[1][1] = z4;

  auto stage = [&](int buf, int kt) {
    {
      int c = tid;                 // 256 chunks: 32 rows x 128B
      int lrow = c >> 3;
      int kb = ks * 1280 + kt * 128 + (((c & 7) * 16) ^ ((lrow & 7) << 4));
      const char* g;
      if (kb < 4096)
        g = (const char*)ctx_bf + (size_t)(b0 + lrow) * 4096 + kb;
      else if (t > 0)
        g = (const char*)h_all + ((size_t)(b0 + lrow) * 32 + (t - 1)) * 1024 + (kb - 4096);
      else
        g = (const char*)zeros_bf + (kb - 4096);
      gld16(g, (char*)&Xs[buf][0] + (size_t)(w * 64) * 16);
    }
#pragma unroll
    for (int j = 0; j < 4; ++j) {   // 1024 chunks: 128 rows x 128B
      int c = j * 256 + tid;
      int lrow = c >> 3;
      int kb = ks * 1280 + kt * 128 + (((c & 7) * 16) ^ ((lrow & 7) << 4));
      const char* g = (const char*)Wcat + (size_t)(row0 + lrow) * 5120 + kb;
      gld16(g, (char*)&Ws[buf][0] + (size_t)(j * 256 + w * 64) * 16);
    }
  };

  stage(0, 0);
  int cur = 0;
  const int lg = l >> 4, lr = l & 15;
  for (int kt = 0; kt < 10; ++kt) {
    __syncthreads();
    if (kt + 1 < 10) stage(cur ^ 1, kt + 1);
#pragma unroll
    for (int k2 = 0; k2 < 2; ++k2) {
      short8 a[2], bb[2];
#pragma unroll
      for (int mi = 0; mi < 2; ++mi) {
        int lrow = mi * 16 + lr;
        int off = (k2 * 64 + lg * 16) ^ ((lrow & 7) << 4);
        a[mi] = *(const short8*)((const char*)&Xs[cur][0] + lrow * 128 + off);
      }
#pragma unroll
      for (int ni = 0; ni < 2; ++ni) {
        int lrow = w * 32 + ni * 16 + lr;
        int off = (k2 * 64 + lg * 16) ^ ((lrow & 7) << 4);
        bb[ni] = *(const short8*)((const char*)&Ws[cur][0] + lrow * 128 + off);
      }
#pragma unroll
      for (int mi = 0; mi < 2; ++mi)
#pragma unroll
        for (int ni = 0; ni < 2; ++ni)
          acc[mi][ni] = __builtin_amdgcn_mfma_f32_16x16x32_bf16(a[mi], bb[ni], acc[mi][ni], 0, 0, 0);
    }
    cur ^= 1;
  }
  float* gp = gates_part + (size_t)ks * 128 * 2048;
#pragma unroll
  for (int mi = 0; mi < 2; ++mi)
#pragma unroll
    for (int ni = 0; ni < 2; ++ni) {
      int col = row0 + w * 32 + ni * 16 + lr;
#pragma unroll
      for (int r = 0; r < 4; ++r) {
        int m = b0 + mi * 16 + lg * 4 + r;
        gp[(size_t)m * 2048 + col] = acc[mi][ni][r];
      }
    }
}

// Final LSTM update (t=32): produces h_32/c_32 -> d_out tail + h_all[b][31].
__global__ __launch_bounds__(512) void final_update(
    const float* __restrict__ gates_part, const float* __restrict__ emb_pre_t,
    float* __restrict__ c_state, u16* __restrict__ h_all,
    float* __restrict__ out_h, float* __restrict__ out_c) {
  const int b = blockIdx.x, j = threadIdx.x;
  const float* gp = gates_part + (size_t)b * 2048 + 4 * j;
  const size_t ss = (size_t)128 * 2048;
  float4 g0 = *(const float4*)gp;
  float4 g1 = *(const float4*)(gp + ss);
  float4 g2 = *(const float4*)(gp + 2 * ss);
  float4 g3 = *(const float4*)(gp + 3 * ss);
  float4 ep = *(const float4*)(emb_pre_t + (size_t)b * 2048 + 4 * j);
  float iv = g0.x + g1.x + g2.x + g3.x + ep.x;
  float fv = g0.y + g1.y + g2.y + g3.y + ep.y;
  float gv = g0.z + g1.z + g2.z + g3.z + ep.z;
  float ov = g0.w + g1.w + g2.w + g3.w + ep.w;
  float c_old = c_state[b * 512 + j];
  float cn = sigm(fv) * c_old + sigm(iv) * fast_tanh(gv);
  float hval = sigm(ov) * fast_tanh(cn);
  out_h[b * 512 + j] = hval;
  out_c[b * 512 + j] = cn;
  h_all[((size_t)b * 32 + 31) * 512 + j] = f2bf(hval);
}

extern "C" void kernel_launch(void* const* d_in, const int* in_sizes, int n_in,
                              void* d_out, int out_size, void* d_ws, size_t ws_size,
                              hipStream_t stream) {
  (void)in_sizes; (void)n_in; (void)out_size; (void)ws_size;
  const float* features = (const float*)d_in[0];
  const int*   captions = (const int*)d_in[1];
  const float* embed_w  = (const float*)d_in[2];
  const float* Waf      = (const float*)d_in[3];
  const float* Wah      = (const float*)d_in[4];
  const float* w_score  = (const float*)d_in[5];
  const float* W_ih     = (const float*)d_in[6];
  const float* W_hh     = (const float*)d_in[7];
  const float* b_ih     = (const float*)d_in[8];
  const float* b_hh     = (const float*)d_in[9];
  const float* W_out    = (const float*)d_in[10];
  const float* b_out    = (const float*)d_in[11];

  // d_out doubles as scratch for phase-1/2 temporaries; the logits GEMM
  // (last) overwrites the whole region, reading only ws buffers.
  float* out = (float*)d_out;
  u16*   feat_bf   = (u16*)out;                    // 12,845,056 bf16
  float* proj_feat = out + 6422528;                // 3,211,264 f32
  float* emb_pre   = out + 9633792;                // 8,388,608 f32
  u16*   Wcat      = (u16*)(out + 18022400);       // 5,242,880 bf16
  u16*   Waf_bf    = (u16*)(out + 20643840);       // 1,048,576 bf16
  u16*   WahT8     = (u16*)(out + 21168128);       //   262,144 bf16
  u16*   Wemb      = (u16*)(out + 21299200);       // 1,048,576 bf16
  float* bias_perm = out + 21823488;               //     2,048 f32
  u16*   emb_bf    = (u16*)(out + 21825536);       // 2,097,152 bf16
  float* out_h     = out + 40960000;
  float* out_c     = out_h + 65536;

  char* wsp = (char*)d_ws;                          // phase-3-live buffers
  u16*   Wout_bf    = (u16*)wsp;  wsp += 10354688;  // [10112][512] bf16
  u16*   h_all      = (u16*)wsp;  wsp += 4194304;   // [128][32][512] bf16
  u16*   ctx_bf     = (u16*)wsp;  wsp += 524288;    // [128][2048] bf16
  float* gates_part = (float*)wsp; wsp += 4194304;  // [4][128][2048] f32
  float* c_state    = (float*)wsp; wsp += 262144;   // [128][512] f32
  u16*   zeros_bf   = (u16*)wsp;  wsp += 1024;      // [512] bf16

  cast_all<<<8192, 256, 0, stream>>>(features, captions, embed_w, Waf, Wah,
      W_ih, W_hh, b_ih, b_hh, W_out, feat_bf, Waf_bf, WahT8, Wcat, Wemb,
      bias_perm, Wout_bf, emb_bf, zeros_bf, c_state);

  // proj_feat [6272][512] = feat_bf [6272][2048] x Waf_bf [512][2048]^T
  gemm128<<<dim3(4, 49), 256, 0, stream>>>(feat_bf, Waf_bf, proj_feat,
                                           nullptr, 2048, 512, 512);
  // emb_pre [4096][2048] = emb_bf [4096][512] x Wemb [2048][512]^T + bias
  gemm128<<<dim3(16, 32), 256, 0, stream>>>(emb_bf, Wemb, emb_pre,
                                            bias_perm, 512, 2048, 2048);

  for (int t = 0; t < 32; ++t) {
    attn_step<<<128, 512, 0, stream>>>(t, gates_part, emb_pre, c_state, h_all,
                                       WahT8, w_score, proj_feat, feat_bf, ctx_bf);
    gates_step<<<dim3(16, 4, 4), 256, 0, stream>>>(t, ctx_bf, h_all, zeros_bf,
                                                   Wcat, gates_part);
  }
  final_update<<<128, 512, 0, stream>>>(gates_part,
      emb_pre + (size_t)31 * 128 * 2048, c_state, h_all, out_h, out_c);

  // logits [4096][10000] = h_all [4096][512] x Wout_bf [10112][512]^T + b_out
  gemm128<<<dim3(79, 32), 256, 0, stream>>>(h_all, Wout_bf, out,
                                            b_out, 512, 10000, 10000);
}